// Round 11
// baseline (196.808 us; speedup 1.0000x reference)
//
#include <hip/hip_runtime.h>

// Problem constants
#define B_    1024
#define C_    128
#define ELL   16
#define EQ    3
#define E_    10
#define P3    23
#define P2    5
#define NROW  48              // EQ*ELL rows per (e,c)
#define NIDX  152             // 136 packed upper-tri (v<=i) quad coeffs + 16 linear
#define KD    28              // folded weight depth: 23 (wmax) + 5 (w2)
#define SRS   (NROW * NIDX)   // 7296 floats per (e,c) S-slice

// ws layout (bytes)
#define WS_CNT   0
#define WS_LIST  64
#define WS_S     65536
#define WS_NEED  ((size_t)WS_S + (size_t)E_ * C_ * SRS * 4)   // ~37.4 MB

// ---------------------------------------------------------------------------
// Bucketing: bucket batch indices by element, pad each bucket to x128 by
// replicating the last real index (k_main then needs no load guards).
__device__ void do_lists(const float* __restrict__ y, int* __restrict__ cnt_g,
                         int* __restrict__ list_g, int t) {
    __shared__ int lcnt[E_];
    if (t < E_) lcnt[t] = 0;
    __syncthreads();
    for (int r = 0; r < 4; ++r) {
        int b = t + 256 * r;
        int e = 0;
        #pragma unroll
        for (int j = 1; j < E_; ++j)
            if (y[b * E_ + j] > 0.5f) e = j;
        int slot = atomicAdd(&lcnt[e], 1);
        list_g[e * B_ + slot] = b;
    }
    __syncthreads();
    if (t < E_) {
        int c0 = lcnt[t];
        cnt_g[t] = c0;
        int last = (c0 > 0) ? list_g[t * B_ + c0 - 1] : 0;
        int cp = (c0 + 127) & ~127;
        if (cp > B_) cp = B_;
        for (int s2 = c0; s2 < cp; ++s2) list_g[t * B_ + s2] = last;
    }
}

// ---------------------------------------------------------------------------
// k_s: build S[e][c][j*NIDX + idx].
//  idx<136 packed (v<=i): S = sum_k (U3[j,v,i,k] + (v!=i)U3[j,i,v,k]) * wmax[e,k,c]
//  idx in [136,152): v=idx-136: S = sum_q U2[j,v,q] * w2[e,q,c]
// grid (49, E, 4): bx<48 -> j=bx (U3[j] block staged to LDS coalesced, LUT
// unranking, threads 0..151 own one idx, 32 c per block-z, coalesced stores);
// block (48,0,0) does bucketing. Replaces r10's divergent while-unrank +
// per-lane scattered global loads (the ~87 us residual).
__global__ __launch_bounds__(256, 2) void k_s(const float* __restrict__ U3,
                                              const float* __restrict__ U2,
                                              const float* __restrict__ wmax,
                                              const float* __restrict__ w2,
                                              const float* __restrict__ y,
                                              float* __restrict__ Sg,
                                              int* __restrict__ cnt_g,
                                              int* __restrict__ list_g) {
    const int t = threadIdx.x;
    if (blockIdx.x == 48) {
        if (blockIdx.y == 0 && blockIdx.z == 0) do_lists(y, cnt_g, list_g, t);
        return;
    }
    __shared__ __align__(16) float U3L[ELL * ELL * P3];  // 23,552 B
    __shared__ __align__(16) float wsm[KD * 32];         //  3,584 B
    __shared__ int LUT[136];

    const int j  = blockIdx.x;
    const int e  = blockIdx.y;
    const int cq = blockIdx.z;

    // stage U3[j] (5888 floats = 1472 f4), fully coalesced
    {
        const float4* src4 = (const float4*)(U3 + (size_t)j * (ELL * ELL * P3));
        float4* dst4 = (float4*)U3L;
        for (int f = t; f < 1472; f += 256) dst4[f] = src4[f];
    }
    // folded weight table (23 wmax + 5 w2) for this (e, c-quarter)
    for (int idx = t; idx < KD * 32; idx += 256) {
        int k = idx >> 5, cc = idx & 31, c = cq * 32 + cc;
        wsm[idx] = (k < 23) ? wmax[(e * P3 + k) * C_ + c]
                            : w2[(e * P2 + (k - 23)) * C_ + c];
    }
    // LUT: rank(v,i) -> (v<<4)|i for v<=i  (no division, no divergent while)
    {
        int v = t >> 4, i = t & 15;
        if (v <= i) {
            int r = v * 16 - (v * (v - 1)) / 2 + (i - v);
            LUT[r] = (v << 4) | i;
        }
    }
    __syncthreads();

    if (t >= NIDX) return;

    float sk[P3], skl[P2];
    if (t < 136) {
        int vi = LUT[t], v = vi >> 4, i = vi & 15;
        const float* pa = &U3L[(v * ELL + i) * P3];
        const float* pb = &U3L[(i * ELL + v) * P3];
        if (v != i) {
            #pragma unroll
            for (int k = 0; k < P3; ++k) sk[k] = pa[k] + pb[k];
        } else {
            #pragma unroll
            for (int k = 0; k < P3; ++k) sk[k] = pa[k];
        }
        #pragma unroll
        for (int q = 0; q < P2; ++q) skl[q] = 0.f;
    } else {
        int v = t - 136;
        #pragma unroll
        for (int k = 0; k < P3; ++k) sk[k] = 0.f;
        #pragma unroll
        for (int q = 0; q < P2; ++q) skl[q] = U2[(size_t)j * (ELL * P2) + v * P2 + q];
    }

    #pragma unroll
    for (int g = 0; g < 8; ++g) {
        float a[4] = {0.f, 0.f, 0.f, 0.f};
        #pragma unroll
        for (int k = 0; k < P3; ++k) {
            float4 wk = *(const float4*)&wsm[k * 32 + 4 * g];
            a[0] += sk[k] * wk.x; a[1] += sk[k] * wk.y;
            a[2] += sk[k] * wk.z; a[3] += sk[k] * wk.w;
        }
        #pragma unroll
        for (int q = 0; q < P2; ++q) {
            float4 wk = *(const float4*)&wsm[(23 + q) * 32 + 4 * g];
            a[0] += skl[q] * wk.x; a[1] += skl[q] * wk.y;
            a[2] += skl[q] * wk.z; a[3] += skl[q] * wk.w;
        }
        #pragma unroll
        for (int q2 = 0; q2 < 4; ++q2) {
            int c = cq * 32 + g * 4 + q2;
            Sg[(size_t)(e * C_ + c) * SRS + j * NIDX + t] = a[q2];
        }
    }
}

// ---------------------------------------------------------------------------
// k_main: one THREAD = one (b,c); one BLOCK = one (c,e,w) -> 16 rows.
// grid (C_, E_, EQ), 128 threads. Factored quadratic form:
//   t2_row = sum_v x_v * (L_v + sum_{i>=v} S_vi * x_i)   -- 152 FMA/row,
// no p[] array (r10's p was rematerialized by the compiler anyway = 2x VALU).
// Rows fully unrolled: jj/v/i all compile-time -> x_own = xr[jj] constant
// index, S loads pipeline across rows. No LDS at all.
// asm memory-barrier at chunk-loop top stops LICM hoisting the chunk-
// invariant S loads (the r5/r6 scratch-spill failure mode, global edition).
__global__ __launch_bounds__(128, 2) void k_main(
    const float* __restrict__ x, const float* __restrict__ Sg,
    const float* __restrict__ U1, const float* __restrict__ w1,
    const int* __restrict__ cnt_g, const int* __restrict__ list_g,
    float* __restrict__ out) {

    const int t = threadIdx.x;
    const int c = blockIdx.x, e = blockIdx.y, w = blockIdx.z;
    const int cnt  = cnt_g[e];
    const int cntp = (cnt + 127) & ~127;
    const float w1s = w1[e * C_ + c];
    const float* sp0 = Sg + (size_t)(e * C_ + c) * SRS + (size_t)w * 16 * NIDX;

    float v1[16];
    #pragma unroll
    for (int jj = 0; jj < 16; ++jj) v1[jj] = U1[w * 16 + jj] * w1s;

    #pragma clang loop unroll(disable)
    for (int base = 0; base < cntp; base += 128) {
        asm volatile("" ::: "memory");   // block LICM of chunk-invariant S loads

        const int b = list_g[e * B_ + base + t];
        const float* xb = x + ((size_t)b * C_ + c) * ELL;

        float xr[16];
        #pragma unroll
        for (int i4 = 0; i4 < 4; ++i4) {
            float4 v = ((const float4*)xb)[i4];
            xr[4 * i4 + 0] = v.x; xr[4 * i4 + 1] = v.y;
            xr[4 * i4 + 2] = v.z; xr[4 * i4 + 3] = v.w;
        }

        float ow = 0.f;
        #pragma unroll
        for (int jj = 0; jj < 16; ++jj) {
            const float4* srow4 = (const float4*)(sp0 + jj * NIDX);  // 16B-aligned
            float sr[NIDX];
            #pragma unroll
            for (int q = 0; q < 38; ++q) *(float4*)(sr + 4 * q) = srow4[q];

            float t2 = 0.f;
            int n = 0;
            #pragma unroll
            for (int v = 0; v < 16; ++v) {
                float inner = sr[136 + v];          // nu=2 linear coeff folded in
                #pragma unroll
                for (int i = v; i < 16; ++i) { inner += sr[n] * xr[i]; ++n; }
                t2 += xr[v] * inner;
            }
            ow += (t2 + v1[jj]) * xr[jj];
        }

        if (base + t < cnt)
            out[(size_t)b * (C_ * EQ) + c * EQ + w] = ow;
    }
}

// ---------------------------------------------------------------------------
extern "C" void kernel_launch(void* const* d_in, const int* in_sizes, int n_in,
                              void* d_out, int out_size, void* d_ws, size_t ws_size,
                              hipStream_t stream) {
    const float* x    = (const float*)d_in[0];
    const float* y    = (const float*)d_in[1];
    const float* U3   = (const float*)d_in[2];
    const float* U2   = (const float*)d_in[3];
    const float* U1   = (const float*)d_in[4];
    const float* wmax = (const float*)d_in[5];
    const float* w2   = (const float*)d_in[6];
    const float* w1   = (const float*)d_in[7];
    float* out = (float*)d_out;
    char*  ws  = (char*)d_ws;

    int*   cnt_g  = (int*)(ws + WS_CNT);
    int*   list_g = (int*)(ws + WS_LIST);
    float* Sg     = (float*)(ws + WS_S);
    (void)ws_size;   // WS_NEED ~37.4 MB; harness ws confirmed >= 66 MB (r1-r10)

    k_s<<<dim3(49, E_, 4), 256, 0, stream>>>(U3, U2, wmax, w2, y, Sg, cnt_g, list_g);
    k_main<<<dim3(C_, E_, EQ), 128, 0, stream>>>(x, Sg, U1, w1, cnt_g, list_g, out);
}

// Round 12
// 138.819 us; speedup vs baseline: 1.4177x; 1.4177x over previous
//
#include <hip/hip_runtime.h>

// Problem constants
#define B_    1024
#define C_    128
#define ELL   16
#define EQ    3
#define E_    10
#define P3    23
#define P2    5
#define NSEG  176            // padded segment row: 16 f4-aligned v-segments
#define RSTR  180            // row stride (180%32=20 -> 8 bank-starts x2 = 2-way, free)
#define SRS   (48 * RSTR)    // 8640 floats per (e,c) S-slice
#define KD    28             // folded weight depth: 23 (wmax) + 5 (w2)

// ws layout (bytes)
#define WS_CNT   0
#define WS_LIST  64
#define WS_S     65536       // S slices: 10*128*8640*4 = 44.2 MB (ws >= 66 MB, r1-r9)

// segment offsets: v-th segment holds [lin_v, Q_vv, Q_v,v+1, .., Q_v,15, pad0s]
// lengths (real) 17-v, padded to x4: {20,16,16,16,16,12,12,12,12,8,8,8,8,4,4,4}
#define SEG_OFF_INIT {0,20,36,52,68,84,96,108,120,132,140,148,156,164,168,172}

// ---------------------------------------------------------------------------
// Bucketing: bucket batch indices by element, pad each bucket to x64 by
// replicating the last real index (k_main then needs no load guards).
__device__ void do_lists(const float* __restrict__ y, int* __restrict__ cnt_g,
                         int* __restrict__ list_g, int t) {
    __shared__ int lcnt[E_];
    if (t < E_) lcnt[t] = 0;
    __syncthreads();
    for (int r = 0; r < 4; ++r) {
        int b = t + 256 * r;
        int e = 0;
        #pragma unroll
        for (int j = 1; j < E_; ++j)
            if (y[b * E_ + j] > 0.5f) e = j;
        int slot = atomicAdd(&lcnt[e], 1);
        list_g[e * B_ + slot] = b;
    }
    __syncthreads();
    if (t < E_) {
        int c0 = lcnt[t];
        cnt_g[t] = c0;
        int last = (c0 > 0) ? list_g[t * B_ + c0 - 1] : 0;
        int cp = (c0 + 63) & ~63;
        if (cp > B_) cp = B_;
        for (int s2 = c0; s2 < cp; ++s2) list_g[t * B_ + s2] = last;
    }
}

// ---------------------------------------------------------------------------
// k_s: build segment-layout S rows (algebra identical to r11, which PASSED):
//  slot (v,0)   : lin_v  = sum_q U2[j,v,q]  * w2[e,q,c]
//  slot (v,l>0) : Q_v,i  = sum_k (U3[j,v,i,k] + (i!=v)*U3[j,i,v,k]) * wmax[e,k,c]
//                 with i = v+l-1; pad slots = 0.
// grid (49, E, 4): bx<48 -> j=bx; block (48,0,0) does bucketing. U3[j] staged
// to LDS coalesced; threads 0..175 own one slot; 32 c per block-z.
__global__ __launch_bounds__(256, 2) void k_s(const float* __restrict__ U3,
                                              const float* __restrict__ U2,
                                              const float* __restrict__ wmax,
                                              const float* __restrict__ w2,
                                              const float* __restrict__ y,
                                              float* __restrict__ Sg,
                                              int* __restrict__ cnt_g,
                                              int* __restrict__ list_g) {
    const int t = threadIdx.x;
    if (blockIdx.x == 48) {
        if (blockIdx.y == 0 && blockIdx.z == 0) do_lists(y, cnt_g, list_g, t);
        return;
    }
    __shared__ __align__(16) float U3L[ELL * ELL * P3];  // 23,552 B
    __shared__ __align__(16) float wsm[KD * 32];         //  3,584 B

    const int j  = blockIdx.x;
    const int e  = blockIdx.y;
    const int cq = blockIdx.z;

    // stage U3[j] (5888 floats = 1472 f4), fully coalesced
    {
        const float4* src4 = (const float4*)(U3 + (size_t)j * (ELL * ELL * P3));
        float4* dst4 = (float4*)U3L;
        for (int f = t; f < 1472; f += 256) dst4[f] = src4[f];
    }
    // folded weight table (23 wmax + 5 w2) for this (e, c-quarter)
    for (int idx = t; idx < KD * 32; idx += 256) {
        int k = idx >> 5, cc = idx & 31, c = cq * 32 + cc;
        wsm[idx] = (k < 23) ? wmax[(e * P3 + k) * C_ + c]
                            : w2[(e * P2 + (k - 23)) * C_ + c];
    }
    __syncthreads();

    if (t >= NSEG) return;

    const int SO[16] = SEG_OFF_INIT;
    int v = 0;
    #pragma unroll
    for (int s = 1; s < 16; ++s) v += (t >= SO[s]) ? 1 : 0;
    const int l    = t - SO[v];
    const int real = 17 - v;           // slot count incl. lin

    float sk[P3], skl[P2];
    #pragma unroll
    for (int k = 0; k < P3; ++k) sk[k] = 0.f;
    #pragma unroll
    for (int q = 0; q < P2; ++q) skl[q] = 0.f;

    if (l == 0) {
        #pragma unroll
        for (int q = 0; q < P2; ++q)
            skl[q] = U2[(size_t)j * (ELL * P2) + v * P2 + q];
    } else if (l < real) {
        int i = v + l - 1;
        const float* pa = &U3L[(v * ELL + i) * P3];
        const float* pb = &U3L[(i * ELL + v) * P3];
        if (i != v) {
            #pragma unroll
            for (int k = 0; k < P3; ++k) sk[k] = pa[k] + pb[k];
        } else {
            #pragma unroll
            for (int k = 0; k < P3; ++k) sk[k] = pa[k];
        }
    }   // else: pad slot -> stays zero

    #pragma unroll
    for (int g = 0; g < 8; ++g) {
        float a[4] = {0.f, 0.f, 0.f, 0.f};
        #pragma unroll
        for (int k = 0; k < P3; ++k) {
            float4 wk = *(const float4*)&wsm[k * 32 + 4 * g];
            a[0] += sk[k] * wk.x; a[1] += sk[k] * wk.y;
            a[2] += sk[k] * wk.z; a[3] += sk[k] * wk.w;
        }
        #pragma unroll
        for (int q = 0; q < P2; ++q) {
            float4 wk = *(const float4*)&wsm[(23 + q) * 32 + 4 * g];
            a[0] += skl[q] * wk.x; a[1] += skl[q] * wk.y;
            a[2] += skl[q] * wk.z; a[3] += skl[q] * wk.w;
        }
        #pragma unroll
        for (int q2 = 0; q2 < 4; ++q2) {
            int c = cq * 32 + g * 4 + q2;
            Sg[(size_t)(e * C_ + c) * SRS + j * RSTR + t] = a[q2];
        }
    }
}

// ---------------------------------------------------------------------------
// k_main: r8's verified loop structure + symmetrized segment rows.
// grid (C_*EQ, E_), 256 threads; bx = c*3+w (w-blocks adjacent: x/L2 reuse).
// xx = t&15 (row within w), bs = t>>4; 4 batch rows/thread -> chunk = 64.
// Per chunk-thread: 44 ds_read_b128 (16-lane 2-way-aliased broadcast) +
// ~768 FMA (vs r8's 64 + 1104) via t2 = sum_v x_v*(lin_v + sum_{i>=v} Q*x_i).
// CRITICAL: __syncthreads() per chunk + unroll(disable) -- without them LICM
// hoists loop-invariant LDS reads -> VGPR blowup -> scratch spill (r5/r6).
__global__ __launch_bounds__(256, 2) void k_main(
    const float* __restrict__ x, const float* __restrict__ Sg,
    const float* __restrict__ U1, const float* __restrict__ w1,
    const int* __restrict__ cnt_g, const int* __restrict__ list_g,
    float* __restrict__ out) {

    __shared__ __align__(16) float V3L[16 * RSTR];   // 11,520 B

    const int t  = threadIdx.x;
    const int bx = blockIdx.x;
    const int w  = bx % 3, c = bx / 3;
    const int e  = blockIdx.y;
    const int xx = t & 15, bs = t >> 4;
    const int cnt  = cnt_g[e];
    const int cntp = (cnt + 63) & ~63;

    // ---- fill V3L: this w's 16 rows = 2880 floats = 720 f4, straight copy
    {
        const float4* src = (const float4*)(Sg + (size_t)(e * C_ + c) * SRS
                                            + (size_t)w * 16 * RSTR);
        float4* dst = (float4*)V3L;
        #pragma unroll
        for (int r = 0; r < 2; ++r) dst[t + 256 * r] = src[t + 256 * r];
        if (t < 208) dst[512 + t] = src[512 + t];
    }
    const float v1x = U1[w * 16 + xx] * w1[e * C_ + c];
    __syncthreads();

    const float* v3p = &V3L[xx * RSTR];
    const int SO[16] = SEG_OFF_INIT;

    // ---- chunk loop: 64 rows per chunk, 4 per thread ----
    #pragma clang loop unroll(disable)
    for (int base = 0; base < cntp; base += 64) {
        __syncthreads();   // anti-LICM liveness pin (see header note)

        const int slot = base + bs * 4;
        int bidx[4];
        #pragma unroll
        for (int r = 0; r < 4; ++r) bidx[r] = list_g[e * B_ + slot + r];

        float xm[4][19];   // x row + 3 zero pads (segment tails index up to 18)
        float xo[4];
        #pragma unroll
        for (int r = 0; r < 4; ++r) {
            const float* xb = x + ((size_t)bidx[r] * C_ + c) * ELL;
            #pragma unroll
            for (int i4 = 0; i4 < 4; ++i4) {
                float4 a = ((const float4*)xb)[i4];
                xm[r][4 * i4 + 0] = a.x; xm[r][4 * i4 + 1] = a.y;
                xm[r][4 * i4 + 2] = a.z; xm[r][4 * i4 + 3] = a.w;
            }
            xm[r][16] = 0.f; xm[r][17] = 0.f; xm[r][18] = 0.f;
            xo[r] = xb[xx];   // own-x element (L1 hit; no dynamic reg index)
        }

        float t2[4] = {0.f, 0.f, 0.f, 0.f};
        #pragma unroll
        for (int v = 0; v < 16; ++v) {
            const int off = SO[v];
            const int nf4 = (v == 0) ? 5 : (v < 5) ? 4 : (v < 9) ? 3 : (v < 13) ? 2 : 1;
            float inner[4];
            {   // first f4: [lin, Q_vv, Q_v,v+1, Q_v,v+2]
                float4 u = *(const float4*)(v3p + off);
                #pragma unroll
                for (int r = 0; r < 4; ++r)
                    inner[r] = u.x + u.y * xm[r][v]
                             + u.z * xm[r][v + 1] + u.w * xm[r][v + 2];
            }
            #pragma unroll
            for (int q = 1; q < nf4; ++q) {
                float4 u = *(const float4*)(v3p + off + 4 * q);
                #pragma unroll
                for (int r = 0; r < 4; ++r) {
                    inner[r] += u.x * xm[r][v + 4 * q - 1];
                    inner[r] += u.y * xm[r][v + 4 * q + 0];
                    inner[r] += u.z * xm[r][v + 4 * q + 1];
                    inner[r] += u.w * xm[r][v + 4 * q + 2];
                }
            }
            #pragma unroll
            for (int r = 0; r < 4; ++r) t2[r] += xm[r][v] * inner[r];
        }

        // out[b,c,w] = sum_xx (t2 + v1[xx]) * x[xx]  -- width-16 butterfly
        float cv[4];
        #pragma unroll
        for (int r = 0; r < 4; ++r) cv[r] = (t2[r] + v1x) * xo[r];
        #pragma unroll
        for (int m = 1; m < 16; m <<= 1) {
            #pragma unroll
            for (int r = 0; r < 4; ++r) cv[r] += __shfl_xor(cv[r], m, 16);
        }
        if (xx == 0) {
            #pragma unroll
            for (int r = 0; r < 4; ++r)
                if (slot + r < cnt)
                    out[(size_t)bidx[r] * (C_ * EQ) + c * EQ + w] = cv[r];
        }
    }
}

// ---------------------------------------------------------------------------
extern "C" void kernel_launch(void* const* d_in, const int* in_sizes, int n_in,
                              void* d_out, int out_size, void* d_ws, size_t ws_size,
                              hipStream_t stream) {
    const float* x    = (const float*)d_in[0];
    const float* y    = (const float*)d_in[1];
    const float* U3   = (const float*)d_in[2];
    const float* U2   = (const float*)d_in[3];
    const float* U1   = (const float*)d_in[4];
    const float* wmax = (const float*)d_in[5];
    const float* w2   = (const float*)d_in[6];
    const float* w1   = (const float*)d_in[7];
    float* out = (float*)d_out;
    char*  ws  = (char*)d_ws;

    int*   cnt_g  = (int*)(ws + WS_CNT);
    int*   list_g = (int*)(ws + WS_LIST);
    float* Sg     = (float*)(ws + WS_S);
    (void)ws_size;   // 44.3 MB needed; harness ws confirmed >= 66 MB (r1-r9)

    k_s<<<dim3(49, E_, 4), 256, 0, stream>>>(U3, U2, wmax, w2, y, Sg, cnt_g, list_g);
    k_main<<<dim3(C_ * EQ, E_), 256, 0, stream>>>(x, Sg, U1, w1, cnt_g, list_g, out);
}